// Round 3
// baseline (720.579 us; speedup 1.0000x reference)
//
#include <hip/hip_runtime.h>

// GCN layer: out = diag(d) * Mat * diag(d) * F, d = rsqrt(rowsum(Mat)+eps).
// index = arange(N) so output is exactly the aggregation for every row.
// R6: eliminate the Abf bf16 copy of Mat entirely (was 128 MB write + ~700 MB
//     re-fetch + an unexplainably slow conversion pass):
//     (a) rowsum-only pass (pure read, roofline ~43 us; also a diagnostic —
//         if it still measures slow, overhead is external to kernel traffic);
//     (b) GEMM reads fp32 Mat directly, reg-stages A with v_cvt_pk_bf16_f32
//         into the same [128][32] bf16 LDS layout (LDS-read traffic unchanged);
//     (c) XCD-grouped block map: the 8 N-tiles of each M-panel co-reside on
//         one XCD -> A panel fetched ~once (FETCH 700 -> ~300 MB predicted);
//     (d) split-K reverted (R5: occupancy unchanged, dur regressed);
//     (e) workspace 176 MB -> 16 MB.

#define N_NODES 8192
#define D_FEAT  1024
#define GCN_EPS 1e-8f

typedef __attribute__((ext_vector_type(8))) short bf16x8;
typedef __attribute__((ext_vector_type(4))) float f32x4;
typedef __attribute__((ext_vector_type(4))) unsigned short u16x4;
typedef __attribute__((ext_vector_type(2))) unsigned int u32x2;

// round-to-nearest-even fp32 -> bf16 (inputs are finite; no NaN handling needed)
__device__ inline unsigned short f2bf(float x) {
  unsigned u = __float_as_uint(x);
  u += 0x7FFFu + ((u >> 16) & 1u);
  return (unsigned short)(u >> 16);
}

// HW pack-convert 2 f32 -> 2 bf16 (RNE); no builtin on gfx950, per-T12 recipe
__device__ inline unsigned cvtpk(float lo, float hi) {
  unsigned r;
  asm("v_cvt_pk_bf16_f32 %0, %1, %2" : "=v"(r) : "v"(lo), "v"(hi));
  return r;
}

// async global->LDS, 16B per lane; lds base must be wave-uniform (HW adds lane*16)
__device__ inline void async_copy16(const void* g, void* l) {
  __builtin_amdgcn_global_load_lds(
      (const __attribute__((address_space(1))) void*)g,
      (__attribute__((address_space(3))) void*)l,
      16, 0, 0);
}

// ---------------- Kernel 1: rowsum only -> dvec ------------------------------
// 2048 blocks x 4 rows, 8 blocks/CU resident. Pure 256 MB read, 32 KB write.
// Roofline ~43 us. If this measures >>43, the slowness is external to traffic.
__global__ __launch_bounds__(256) void rowsum(
    const float* __restrict__ Mat, float* __restrict__ dvec) {
  const int tid = threadIdx.x;
  const int lane = tid & 63, wave = tid >> 6;
  __shared__ float red[4];
#pragma unroll 1
  for (int rr = 0; rr < 4; ++rr) {
    const int row = blockIdx.x * 4 + rr;
    const f32x4* src = (const f32x4*)(Mat + (size_t)row * N_NODES);
    float s = 0.f;
#pragma unroll
    for (int i = 0; i < 8; ++i) {
      f32x4 v = src[tid + i * 256];
      s += (v.x + v.y) + (v.z + v.w);
    }
#pragma unroll
    for (int off = 32; off > 0; off >>= 1) s += __shfl_down(s, off);
    if (lane == 0) red[wave] = s;
    __syncthreads();
    if (tid == 0) {
      float t = (red[0] + red[1]) + (red[2] + red[3]);
      dvec[row] = 1.0f / sqrtf(t + GCN_EPS);  // rowsum ~4096, never inf
    }
    __syncthreads();  // red[] reused next row
  }
}

// ---------------- Kernel 2: Fst[n][j] = bf16(d[j] * F[j][n]) -----------------
// 64x64 LDS-tiled transpose, 256 threads. 48 MB total -> ~15 us ideal.
__global__ __launch_bounds__(256) void scale_transpose(
    const float* __restrict__ F, const float* __restrict__ dvec,
    unsigned short* __restrict__ Fst) {
  __shared__ float tile[64][65];
  const int t = threadIdx.x;
  const int n0 = blockIdx.x * 64;  // feature dim
  const int j0 = blockIdx.y * 64;  // node dim
  const int jr = t >> 4;           // 0..15
  const int c = t & 15;            // 0..15 (16B chunk)
#pragma unroll
  for (int i = 0; i < 4; ++i) {
    int jj = jr + 16 * i;
    float dv = dvec[j0 + jj];
    f32x4 v = *(const f32x4*)(F + (size_t)(j0 + jj) * D_FEAT + n0 + c * 4);
    tile[jj][c * 4 + 0] = v.x * dv;
    tile[jj][c * 4 + 1] = v.y * dv;
    tile[jj][c * 4 + 2] = v.z * dv;
    tile[jj][c * 4 + 3] = v.w * dv;
  }
  __syncthreads();
#pragma unroll
  for (int i = 0; i < 4; ++i) {
    int nn = jr + 16 * i;
    u16x4 o;
    o.x = f2bf(tile[c * 4 + 0][nn]);
    o.y = f2bf(tile[c * 4 + 1][nn]);
    o.z = f2bf(tile[c * 4 + 2][nn]);
    o.w = f2bf(tile[c * 4 + 3][nn]);
    *(u16x4*)(Fst + (size_t)(n0 + nn) * N_NODES + j0 + c * 4) = o;
  }
}

// ---------------- Kernel 3: C[m][n] = d[m] * sum_k Mat[m][k]*Bt[n][k] --------
// m97 structure, A straight from fp32 Mat: 128x128 tile, BK=32, 4 waves of
// 64x64, 16x16x32 bf16 MFMA. A: reg-staged (coalesced 128B f32 reads, 8x
// v_cvt_pk_bf16_f32, ds_write_b64) into [128][32] bf16 LDS (same layout /
// LDS-read traffic as before). B: global_load_lds width=16 (unchanged).
// XCD-grouped map: slot&7 = XCD (round-robin heuristic); XCD x owns M-panels
// [8x,8x+8) so the 8 N-tiles sharing a panel share that XCD's L2.
__global__ __launch_bounds__(256) void gemm_af32(
    const float* __restrict__ Mat,           // [8192][8192] fp32
    const unsigned short* __restrict__ Bt,   // [1024][8192] bf16 (F^T, d-scaled)
    const float* __restrict__ dvec,
    float* __restrict__ C) {                 // [8192][1024] fp32
  const int K = N_NODES;
  __shared__ __align__(16) unsigned short As[128 * 32];  // 8 KB, [m][k] bf16
  __shared__ __align__(16) unsigned short Bs[128 * 32];  // 8 KB, [n][k] bf16

  const int tid = threadIdx.x;
  const int wave = tid >> 6, lane = tid & 63;
  // bijective XCD-group swizzle (nwg=512, 512%8==0)
  const int slot = blockIdx.x;
  const int wg = (slot & 7) * 64 + (slot >> 3);
  const int tileM = (wg >> 3) * 128;   // 64 M-panels
  const int tileN = (wg & 7) * 128;    // 8 N-tiles
  const int wm = (wave >> 1) * 64, wn = (wave & 1) * 64;  // wave tile: 64m x 64n
  const int lrow = lane & 15, quad = lane >> 4;

  // A staging: thread t covers rows (t>>3)+{0,32,64,96}, cols (t&7)*4..+4.
  // Per load instruction: 8 lanes x 16B = 128B contiguous per row (coalesced).
  const float* gA = Mat + (size_t)(tileM + (tid >> 3)) * K + (tid & 7) * 4;
  // B staging chunks (16B = 8 elems): row = c>>2, k8 = (c&3)*8 (proven layout)
  const unsigned short* gB0 = Bt + (size_t)(tileN + (tid >> 2)) * K + (tid & 3) * 8;
  const unsigned short* gB1 = Bt + (size_t)(tileN + 64 + (tid >> 2)) * K + (tid & 3) * 8;
  unsigned short* lB0 = &Bs[wave * 512];         // wave-uniform bases
  unsigned short* lB1 = &Bs[2048 + wave * 512];
  unsigned short* lA = &As[(tid >> 3) * 32 + (tid & 7) * 4];  // +p*1024 per pass

  f32x4 acc[4][4] = {};

  for (int k0 = 0; k0 < K; k0 += 32) {
    __syncthreads();  // previous compute's ds_reads done before overwriting LDS
    // issue longest-latency loads first
    f32x4 a0 = *(const f32x4*)(gA + k0);
    f32x4 a1 = *(const f32x4*)(gA + k0 + (size_t)32 * K);
    f32x4 a2 = *(const f32x4*)(gA + k0 + (size_t)64 * K);
    f32x4 a3 = *(const f32x4*)(gA + k0 + (size_t)96 * K);
    async_copy16(gB0 + k0, lB0);
    async_copy16(gB1 + k0, lB1);
    // convert + stage A (compiler inserts per-use vmcnt waits)
    u32x2 w;
    w.x = cvtpk(a0.x, a0.y); w.y = cvtpk(a0.z, a0.w); *(u32x2*)(lA + 0 * 1024) = w;
    w.x = cvtpk(a1.x, a1.y); w.y = cvtpk(a1.z, a1.w); *(u32x2*)(lA + 1 * 1024) = w;
    w.x = cvtpk(a2.x, a2.y); w.y = cvtpk(a2.z, a2.w); *(u32x2*)(lA + 2 * 1024) = w;
    w.x = cvtpk(a3.x, a3.y); w.y = cvtpk(a3.z, a3.w); *(u32x2*)(lA + 3 * 1024) = w;
    __syncthreads();  // drains vmcnt (B copies) + lgkmcnt (A writes)

    bf16x8 af[4], bfr[4];
#pragma unroll
    for (int mi = 0; mi < 4; ++mi)
      af[mi] = *(const bf16x8*)&As[(wm + mi * 16 + lrow) * 32 + quad * 8];
#pragma unroll
    for (int ni = 0; ni < 4; ++ni)
      bfr[ni] = *(const bf16x8*)&Bs[(wn + ni * 16 + lrow) * 32 + quad * 8];
#pragma unroll
    for (int mi = 0; mi < 4; ++mi)
#pragma unroll
      for (int ni = 0; ni < 4; ++ni)
        acc[mi][ni] = __builtin_amdgcn_mfma_f32_16x16x32_bf16(
            af[mi], bfr[ni], acc[mi][ni], 0, 0, 0);
  }

  // epilogue: C/D layout col=lane&15, row=quad*4+reg [verified m89/m91]
#pragma unroll
  for (int mi = 0; mi < 4; ++mi) {
#pragma unroll
    for (int r = 0; r < 4; ++r) {
      int row = tileM + wm + mi * 16 + quad * 4 + r;
      float dv = dvec[row];
#pragma unroll
      for (int ni = 0; ni < 4; ++ni) {
        int col = tileN + wn + ni * 16 + lrow;
        C[(size_t)row * D_FEAT + col] = dv * acc[mi][ni][r];
      }
    }
  }
}

extern "C" void kernel_launch(void* const* d_in, const int* in_sizes, int n_in,
                              void* d_out, int out_size, void* d_ws, size_t ws_size,
                              hipStream_t stream) {
  const float* F = (const float*)d_in[0];     // [8192][1024]
  const float* Mat = (const float*)d_in[1];   // [8192][8192]
  // d_in[2] (index) is arange(N) -> output is the aggregation for every row; unused.
  float* out = (float*)d_out;

  // workspace: d (32 KB) | Fst bf16 (16 MB) = 16.03 MB total (was 176 MB)
  char* ws = (char*)d_ws;
  float* dvec = (float*)ws;
  unsigned short* Fst = (unsigned short*)(ws + 32768);

  rowsum<<<N_NODES / 4, 256, 0, stream>>>(Mat, dvec);
  scale_transpose<<<dim3(D_FEAT / 64, N_NODES / 64), 256, 0, stream>>>(F, dvec, Fst);
  gemm_af32<<<512, 256, 0, stream>>>(Mat, Fst, dvec, out);
}

// Round 4
// 685.744 us; speedup vs baseline: 1.0508x; 1.0508x over previous
//
#include <hip/hip_runtime.h>

// GCN layer: out = diag(d) * Mat * diag(d) * F, d = rsqrt(rowsum(Mat)+eps).
// index = arange(N) so output is exactly the aggregation for every row.
// R7: gemm = R4's all-async 2-barrier m97 structure + R6's traffic wins:
//     - A staged as RAW FP32 via global_load_lds (async DMA, drained at the
//       existing barrier) -> no synchronous load chain (R6's 353us mistake);
//     - bf16 conversion moved to fragment-read time (16 v_cvt_pk per thread
//       per K-step, noise vs 16 MFMA);
//     - fp32 A rows (128B stride) would be a 16-way LDS bank conflict: XOR
//       swizzle sub^=(row&7) via PRE-SWIZZLED GLOBAL SOURCE (m173 pattern,
//       gload_lds dest stays linear); B likewise sub^=(row&3) -> both ~2-way;
//     - XCD-grouped block map kept (FETCH 700->198 MB in R6).
//     Occupancy is register-capped at 2 blocks/CU (R5 proved grid-doubling
//     changes nothing) -> optimize per-wave critical path, not block count.

#define N_NODES 8192
#define D_FEAT  1024
#define GCN_EPS 1e-8f

typedef __attribute__((ext_vector_type(8))) short bf16x8;
typedef __attribute__((ext_vector_type(4))) float f32x4;
typedef __attribute__((ext_vector_type(4))) unsigned short u16x4;

// round-to-nearest-even fp32 -> bf16 (inputs are finite; no NaN handling needed)
__device__ inline unsigned short f2bf(float x) {
  unsigned u = __float_as_uint(x);
  u += 0x7FFFu + ((u >> 16) & 1u);
  return (unsigned short)(u >> 16);
}

// HW pack-convert 2 f32 -> 2 bf16 (RNE): D.lo16=cvt(lo), D.hi16=cvt(hi)
__device__ inline unsigned cvtpk(float lo, float hi) {
  unsigned r;
  asm("v_cvt_pk_bf16_f32 %0, %1, %2" : "=v"(r) : "v"(lo), "v"(hi));
  return r;
}

// async global->LDS, 16B per lane; lds base must be wave-uniform (HW adds lane*16)
__device__ inline void async_copy16(const void* g, void* l) {
  __builtin_amdgcn_global_load_lds(
      (const __attribute__((address_space(1))) void*)g,
      (__attribute__((address_space(3))) void*)l,
      16, 0, 0);
}

// ---------------- Kernel 1: rowsum only -> dvec ------------------------------
// 2048 blocks x 4 rows, 8 blocks/CU resident. Pure 256 MB read, 32 KB write.
__global__ __launch_bounds__(256) void rowsum(
    const float* __restrict__ Mat, float* __restrict__ dvec) {
  const int tid = threadIdx.x;
  const int lane = tid & 63, wave = tid >> 6;
  __shared__ float red[4];
#pragma unroll 1
  for (int rr = 0; rr < 4; ++rr) {
    const int row = blockIdx.x * 4 + rr;
    const f32x4* src = (const f32x4*)(Mat + (size_t)row * N_NODES);
    float s = 0.f;
#pragma unroll
    for (int i = 0; i < 8; ++i) {
      f32x4 v = src[tid + i * 256];
      s += (v.x + v.y) + (v.z + v.w);
    }
#pragma unroll
    for (int off = 32; off > 0; off >>= 1) s += __shfl_down(s, off);
    if (lane == 0) red[wave] = s;
    __syncthreads();
    if (tid == 0) {
      float t = (red[0] + red[1]) + (red[2] + red[3]);
      dvec[row] = 1.0f / sqrtf(t + GCN_EPS);  // rowsum ~4096, never inf
    }
    __syncthreads();  // red[] reused next row
  }
}

// ---------------- Kernel 2: Fst[n][j] = bf16(d[j] * F[j][n]) -----------------
// 64x64 LDS-tiled transpose, 256 threads. 48 MB total.
__global__ __launch_bounds__(256) void scale_transpose(
    const float* __restrict__ F, const float* __restrict__ dvec,
    unsigned short* __restrict__ Fst) {
  __shared__ float tile[64][65];
  const int t = threadIdx.x;
  const int n0 = blockIdx.x * 64;  // feature dim
  const int j0 = blockIdx.y * 64;  // node dim
  const int jr = t >> 4;           // 0..15
  const int c = t & 15;            // 0..15 (16B chunk)
#pragma unroll
  for (int i = 0; i < 4; ++i) {
    int jj = jr + 16 * i;
    float dv = dvec[j0 + jj];
    f32x4 v = *(const f32x4*)(F + (size_t)(j0 + jj) * D_FEAT + n0 + c * 4);
    tile[jj][c * 4 + 0] = v.x * dv;
    tile[jj][c * 4 + 1] = v.y * dv;
    tile[jj][c * 4 + 2] = v.z * dv;
    tile[jj][c * 4 + 3] = v.w * dv;
  }
  __syncthreads();
#pragma unroll
  for (int i = 0; i < 4; ++i) {
    int nn = jr + 16 * i;
    u16x4 o;
    o.x = f2bf(tile[c * 4 + 0][nn]);
    o.y = f2bf(tile[c * 4 + 1][nn]);
    o.z = f2bf(tile[c * 4 + 2][nn]);
    o.w = f2bf(tile[c * 4 + 3][nn]);
    *(u16x4*)(Fst + (size_t)(n0 + nn) * N_NODES + j0 + c * 4) = o;
  }
}

// ---------------- Kernel 3: C[m][n] = d[m] * sum_k Mat[m][k]*Bt[n][k] --------
// 128x128 tile, BK=32, 4 waves of 64x64, 16x16x32 bf16 MFMA.
// A: fp32 [128][32] in LDS via gload_lds (16 KB), XOR-swizzled sub^=(row&7)
//    through pre-swizzled global source; converted to bf16 at frag read.
// B: bf16 [128][32] via gload_lds (8 KB), XOR-swizzled sub^=(row&3).
// XCD-grouped map: XCD x owns M-panels [8x,8x+8); its 64 resident blocks
// (2/CU x 32 CU) are exactly one panel-group -> A fetched ~once via L2.
__global__ __launch_bounds__(256) void gemm_af32(
    const float* __restrict__ Mat,           // [8192][8192] fp32
    const unsigned short* __restrict__ Bt,   // [1024][8192] bf16 (F^T, d-scaled)
    const float* __restrict__ dvec,
    float* __restrict__ C) {                 // [8192][1024] fp32
  const int K = N_NODES;
  __shared__ __align__(16) float Asf[128 * 32];          // 16 KB fp32 [m][k]
  __shared__ __align__(16) unsigned short Bs[128 * 32];  // 8 KB bf16 [n][k]

  const int tid = threadIdx.x;
  const int wave = tid >> 6, lane = tid & 63;
  // bijective XCD-group swizzle (nwg=512, 512%8==0): slot&7 = XCD
  const int slot = blockIdx.x;
  const int wg = (slot & 7) * 64 + (slot >> 3);
  const int tileM = (wg >> 3) * 128;   // 64 M-panels
  const int tileN = (wg & 7) * 128;    // 8 N-tiles per panel
  const int wm = (wave >> 1) * 64, wn = (wave & 1) * 64;  // wave tile: 64m x 64n
  const int lrow = lane & 15, quad = lane >> 4;

  // ---- A staging: 1024 fp32 16B-chunks; thread t pass p -> chunk p*256+t
  //      row = (t>>3)+32p, sub = t&7. Source pre-swizzled: fetch global sub
  //      (t&7)^(row&7) so read-side addr^((row&7)<<4) sees linear data.
  //      (row&7) == ((t>>3)&7) for all p since 32p = 0 mod 8.
  const int ass = ((tid & 7) ^ ((tid >> 3) & 7)) * 4;  // f32 col within 32-col row
  const float* gA = Mat + (size_t)(tileM + (tid >> 3)) * K + ass;
  float* lA = &Asf[wave * 256];  // + p*1024 per pass (chunk = p*256 + w*64 + lane)

  // ---- B staging: 512 bf16 16B-chunks; chunk c -> row c>>2, sub c&3.
  //      Source pre-swizzled: fetch global sub (t&3)^(row&3); row&3==(t>>2)&3.
  const int bss = ((tid & 3) ^ ((tid >> 2) & 3)) * 8;  // bf16 col within 32-col row
  const unsigned short* gB0 = Bt + (size_t)(tileN + (tid >> 2)) * K + bss;
  const unsigned short* gB1 = Bt + (size_t)(tileN + 64 + (tid >> 2)) * K + bss;
  unsigned short* lB0 = &Bs[wave * 512];
  unsigned short* lB1 = &Bs[2048 + wave * 512];

  // ---- read-side swizzled sub-block indices (row&7 == lrow&7, row&3 == lrow&3
  //      for every fragment row: wm, wn, mi*16, ni*16 are all 0 mod 8/4)
  const int asub0 = ((quad * 2) ^ (lrow & 7)) * 4;      // f32 idx of k-bytes 0..15
  const int asub1 = ((quad * 2 + 1) ^ (lrow & 7)) * 4;  // f32 idx of k-bytes 16..31
  const int bsub = (quad ^ (lrow & 3)) * 8;             // bf16 idx of the 16B frag

  f32x4 acc[4][4] = {};

  for (int k0 = 0; k0 < K; k0 += 32) {
    __syncthreads();  // previous compute's ds_reads done before overwriting LDS
#pragma unroll
    for (int p = 0; p < 4; ++p)
      async_copy16(gA + k0 + (size_t)(32 * p) * K, lA + p * 1024);
    async_copy16(gB0 + k0, lB0);
    async_copy16(gB1 + k0, lB1);
    __syncthreads();  // compiler drains vmcnt before s_barrier

    bf16x8 af[4], bfr[4];
#pragma unroll
    for (int mi = 0; mi < 4; ++mi) {
      const float* ap = &Asf[(wm + mi * 16 + lrow) * 32];
      f32x4 lo = *(const f32x4*)(ap + asub0);
      f32x4 hi = *(const f32x4*)(ap + asub1);
      union { unsigned u[4]; bf16x8 v; } pk;
      pk.u[0] = cvtpk(lo.x, lo.y);
      pk.u[1] = cvtpk(lo.z, lo.w);
      pk.u[2] = cvtpk(hi.x, hi.y);
      pk.u[3] = cvtpk(hi.z, hi.w);
      af[mi] = pk.v;
    }
#pragma unroll
    for (int ni = 0; ni < 4; ++ni)
      bfr[ni] = *(const bf16x8*)&Bs[(wn + ni * 16 + lrow) * 32 + bsub];
#pragma unroll
    for (int mi = 0; mi < 4; ++mi)
#pragma unroll
      for (int ni = 0; ni < 4; ++ni)
        acc[mi][ni] = __builtin_amdgcn_mfma_f32_16x16x32_bf16(
            af[mi], bfr[ni], acc[mi][ni], 0, 0, 0);
  }

  // epilogue: C/D layout col=lane&15, row=quad*4+reg [verified m89/m91]
#pragma unroll
  for (int mi = 0; mi < 4; ++mi) {
#pragma unroll
    for (int r = 0; r < 4; ++r) {
      int row = tileM + wm + mi * 16 + quad * 4 + r;
      float dv = dvec[row];
#pragma unroll
      for (int ni = 0; ni < 4; ++ni) {
        int col = tileN + wn + ni * 16 + lrow;
        C[(size_t)row * D_FEAT + col] = dv * acc[mi][ni][r];
      }
    }
  }
}

extern "C" void kernel_launch(void* const* d_in, const int* in_sizes, int n_in,
                              void* d_out, int out_size, void* d_ws, size_t ws_size,
                              hipStream_t stream) {
  const float* F = (const float*)d_in[0];     // [8192][1024]
  const float* Mat = (const float*)d_in[1];   // [8192][8192]
  // d_in[2] (index) is arange(N) -> output is the aggregation for every row; unused.
  float* out = (float*)d_out;

  // workspace: d (32 KB) | Fst bf16 (16 MB)
  char* ws = (char*)d_ws;
  float* dvec = (float*)ws;
  unsigned short* Fst = (unsigned short*)(ws + 32768);

  rowsum<<<N_NODES / 4, 256, 0, stream>>>(Mat, dvec);
  scale_transpose<<<dim3(D_FEAT / 64, N_NODES / 64), 256, 0, stream>>>(F, dvec, Fst);
  gemm_af32<<<512, 256, 0, stream>>>(Mat, Fst, dvec, out);
}

// Round 6
// 628.496 us; speedup vs baseline: 1.1465x; 1.0911x over previous
//
#include <hip/hip_runtime.h>

// GCN layer: out = diag(d) * Mat * diag(d) * F, d = rsqrt(rowsum(Mat)+eps).
// index = arange(N) so output is exactly the aggregation for every row.
// R9: cooperative launch is DEAD (R8: launch silently no-opped -> zeros).
//     Pipeline collapsed to 2 dispatches with only block-local dependencies:
//     K1 prep_fused: block b owns rows [16b,16b+16): rowsum -> d (block-local),
//        bf16-convert those Mat rows (Abf), and write the d-scaled transposed
//        F-slab Fst[*][16b..16b+16) via a [64n][18j] LDS tile (~2-way banks).
//        One Mat read serves BOTH rowsum and convert (was 2 reads in R4..R7).
//     K2 gemm: R4's bench-passed structure (232 us) + R6/R7's bench-passed
//        XCD-grouped map (198 MB fetch). d[m] applied in epilogue.
//     With 2 kernel names, BOTH appear in top-5 -> the constant ~370 us aux
//     region finally gets per-dispatch counter visibility.

#define N_NODES 8192
#define D_FEAT  1024
#define GCN_EPS 1e-8f

typedef __attribute__((ext_vector_type(8))) short bf16x8;
typedef __attribute__((ext_vector_type(4))) float f32x4;
typedef __attribute__((ext_vector_type(4))) unsigned short u16x4;

// round-to-nearest-even fp32 -> bf16 (inputs are finite; no NaN handling needed)
__device__ inline unsigned short f2bf(float x) {
  unsigned u = __float_as_uint(x);
  u += 0x7FFFu + ((u >> 16) & 1u);
  return (unsigned short)(u >> 16);
}

// async global->LDS, 16B per lane; lds base must be wave-uniform (HW adds lane*16)
__device__ inline void async_copy16(const void* g, void* l) {
  __builtin_amdgcn_global_load_lds(
      (const __attribute__((address_space(1))) void*)g,
      (__attribute__((address_space(3))) void*)l,
      16, 0, 0);
}

// ---------------- Kernel 1: fused prep --------------------------------------
// 512 blocks x 256 threads; block b owns node rows J = [16b, 16b+16).
// Phase A (per row): 256 thr x 8 f32x4 coalesced read of Mat row -> rowsum
//   (shfl + LDS reduce) AND bf16 store to Abf. d -> dvec (global) + dloc (LDS).
// Phase B (16 chunks of 64 n): tile[n][j] f32 [64][18] (+2 pad -> ~2-way max):
//   write: thread (r=tid>>4, c=tid&15) stages F[j0+r][nc*64+c*4 ..+4] * d[r];
//   read:  thread (nn=tid>>2, jq=tid&3) packs 4 j-consecutive bf16 and stores
//   u16x4 to Fst[nc*64+nn][j0+jq*4] (32B segments per 4-lane group).
__global__ __launch_bounds__(256) void prep_fused(
    const float* __restrict__ Mat, const float* __restrict__ F,
    unsigned short* __restrict__ Abf, unsigned short* __restrict__ Fst,
    float* __restrict__ dvec) {
  __shared__ float red[4];
  __shared__ float dloc[16];
  __shared__ float tile[64][18];
  const int tid = threadIdx.x;
  const int lane = tid & 63, wave = tid >> 6;
  const int j0 = blockIdx.x * 16;

  // ---- Phase A: rowsum + convert, rows j0..j0+15 ----
#pragma unroll 1
  for (int rr = 0; rr < 16; ++rr) {
    const int row = j0 + rr;
    const f32x4* src = (const f32x4*)(Mat + (size_t)row * N_NODES);
    u16x4* dst = (u16x4*)(Abf + (size_t)row * N_NODES);
    float s = 0.f;
#pragma unroll
    for (int i = 0; i < 8; ++i) {
      f32x4 v = src[tid + i * 256];
      s += (v.x + v.y) + (v.z + v.w);
      u16x4 o;
      o.x = f2bf(v.x); o.y = f2bf(v.y); o.z = f2bf(v.z); o.w = f2bf(v.w);
      dst[tid + i * 256] = o;
    }
#pragma unroll
    for (int off = 32; off > 0; off >>= 1) s += __shfl_down(s, off);
    if (lane == 0) red[wave] = s;
    __syncthreads();
    if (tid == 0) {
      float t = (red[0] + red[1]) + (red[2] + red[3]);
      float dv = 1.0f / sqrtf(t + GCN_EPS);  // rowsum ~4096, never inf
      dvec[row] = dv;
      dloc[rr] = dv;
    }
    __syncthreads();  // red[] reused; dloc visible before phase B
  }

  // ---- Phase B: d-scaled transpose of F rows j0..j0+15 into Fst columns ----
  const int r = tid >> 4, c = tid & 15;   // staging role: row r, col-chunk c
  const int nn = tid >> 2, jq = tid & 3;  // output role: n nn, j-quad jq
  const float dv = dloc[r];
#pragma unroll 1
  for (int nc = 0; nc < 16; ++nc) {
    f32x4 v = *(const f32x4*)(F + (size_t)(j0 + r) * D_FEAT + nc * 64 + c * 4);
    tile[c * 4 + 0][r] = v.x * dv;
    tile[c * 4 + 1][r] = v.y * dv;
    tile[c * 4 + 2][r] = v.z * dv;
    tile[c * 4 + 3][r] = v.w * dv;
    __syncthreads();
    u16x4 o;
    o.x = f2bf(tile[nn][jq * 4 + 0]);
    o.y = f2bf(tile[nn][jq * 4 + 1]);
    o.z = f2bf(tile[nn][jq * 4 + 2]);
    o.w = f2bf(tile[nn][jq * 4 + 3]);
    *(u16x4*)(Fst + (size_t)(nc * 64 + nn) * N_NODES + j0 + jq * 4) = o;
    __syncthreads();  // tile reused next chunk
  }
}

// ---------------- Kernel 2: C[m][n] = d[m] * sum_k A[m][k]*Bt[n][k] ----------
// R4's bench-passed structure: 128x128 tile, BK=32, 4 waves of 64x64, 16x16x32
// bf16 MFMA, global_load_lds width=16 staging, 2-barrier K-loop.
// + R6/R7's bench-passed XCD-grouped map (FETCH 700 -> ~200 MB).
__global__ __launch_bounds__(256) void gemm_bt(
    const unsigned short* __restrict__ A,    // [8192][8192] bf16
    const unsigned short* __restrict__ Bt,   // [1024][8192] bf16 (F^T, d-scaled)
    const float* __restrict__ dvec,
    float* __restrict__ C) {                 // [8192][1024] fp32
  const int K = N_NODES;
  __shared__ __align__(16) unsigned short As[128 * 32];  // 8 KB, [m][k]
  __shared__ __align__(16) unsigned short Bs[128 * 32];  // 8 KB, [n][k]

  const int tid = threadIdx.x;
  const int wave = tid >> 6, lane = tid & 63;
  // bijective XCD-group swizzle (nwg=512, 512%8==0): slot&7 = XCD;
  // XCD x owns M-panels [8x,8x+8) -> the 8 N-tiles of a panel share its L2.
  const int slot = blockIdx.x;
  const int wg = (slot & 7) * 64 + (slot >> 3);
  const int tileM = (wg >> 3) * 128;
  const int tileN = (wg & 7) * 128;
  const int wm = (wave >> 1) * 64, wn = (wave & 1) * 64;  // wave tile: 64m x 64n
  const int lrow = lane & 15, quad = lane >> 4;

  // staging: 512 16B-chunks each; chunk c -> row c>>2, k8 = (c&3)*8 (linear)
  const unsigned short* gA0 = A + (size_t)(tileM + (tid >> 2)) * K + (tid & 3) * 8;
  const unsigned short* gA1 = A + (size_t)(tileM + 64 + (tid >> 2)) * K + (tid & 3) * 8;
  const unsigned short* gB0 = Bt + (size_t)(tileN + (tid >> 2)) * K + (tid & 3) * 8;
  const unsigned short* gB1 = Bt + (size_t)(tileN + 64 + (tid >> 2)) * K + (tid & 3) * 8;
  unsigned short* lA0 = &As[wave * 512];  // wave-uniform bases (lane*16B by HW)
  unsigned short* lA1 = &As[2048 + wave * 512];
  unsigned short* lB0 = &Bs[wave * 512];
  unsigned short* lB1 = &Bs[2048 + wave * 512];

  f32x4 acc[4][4] = {};

  for (int k0 = 0; k0 < K; k0 += 32) {
    __syncthreads();  // previous compute's ds_reads done before overwrite
    async_copy16(gA0 + k0, lA0);
    async_copy16(gA1 + k0, lA1);
    async_copy16(gB0 + k0, lB0);
    async_copy16(gB1 + k0, lB1);
    __syncthreads();  // compiler drains vmcnt before s_barrier

    bf16x8 af[4], bfr[4];
#pragma unroll
    for (int mi = 0; mi < 4; ++mi)
      af[mi] = *(const bf16x8*)&As[(wm + mi * 16 + lrow) * 32 + quad * 8];
#pragma unroll
    for (int ni = 0; ni < 4; ++ni)
      bfr[ni] = *(const bf16x8*)&Bs[(wn + ni * 16 + lrow) * 32 + quad * 8];
#pragma unroll
    for (int mi = 0; mi < 4; ++mi)
#pragma unroll
      for (int ni = 0; ni < 4; ++ni)
        acc[mi][ni] = __builtin_amdgcn_mfma_f32_16x16x32_bf16(
            af[mi], bfr[ni], acc[mi][ni], 0, 0, 0);
  }

  // epilogue: C/D layout col=lane&15, row=quad*4+reg [verified m89/m91]
#pragma unroll
  for (int mi = 0; mi < 4; ++mi) {
#pragma unroll
    for (int r = 0; r < 4; ++r) {
      int row = tileM + wm + mi * 16 + quad * 4 + r;
      float dv = dvec[row];
#pragma unroll
      for (int ni = 0; ni < 4; ++ni) {
        int col = tileN + wn + ni * 16 + lrow;
        C[(size_t)row * D_FEAT + col] = dv * acc[mi][ni][r];
      }
    }
  }
}

extern "C" void kernel_launch(void* const* d_in, const int* in_sizes, int n_in,
                              void* d_out, int out_size, void* d_ws, size_t ws_size,
                              hipStream_t stream) {
  const float* F = (const float*)d_in[0];     // [8192][1024]
  const float* Mat = (const float*)d_in[1];   // [8192][8192]
  // d_in[2] (index) is arange(N) -> output is the aggregation for every row; unused.
  float* out = (float*)d_out;

  // workspace: dvec (32 KB) | Fst bf16 (16 MB) | Abf bf16 (128 MB) = 144.06 MB
  char* ws = (char*)d_ws;
  float* dvec = (float*)ws;
  unsigned short* Fst = (unsigned short*)(ws + 32768);
  unsigned short* Abf = (unsigned short*)(ws + 32768 + (size_t)D_FEAT * N_NODES * 2);

  prep_fused<<<512, 256, 0, stream>>>(Mat, F, Abf, Fst, dvec);
  gemm_bt<<<512, 256, 0, stream>>>(Abf, Fst, dvec, out);
}